// Round 1
// baseline (57.276 us; speedup 1.0000x reference)
//
#include <hip/hip_runtime.h>

#define B 4
#define N 1024
#define K 100
#define F 42
#define H 64

// ---------------------------------------------------------------------------
// Kernel 1: per-atom MLP forward + analytic input gradient.
// One wave (64 lanes) per atom; lane i owns hidden unit i (H == 64).
//   h1 = tanh(x@W1+b1); h2 = tanh(h1@W2+b2); E = h2@W3 + b3
//   g2 = W3 * (1-h2^2); g1 = (W2 @ g2) * (1-h1^2); dE/dx_f = sum_i W1[f,i] g1[i]
// ---------------------------------------------------------------------------
__global__ __launch_bounds__(256) void mlp_kernel(
    const float* __restrict__ image,
    const float* __restrict__ W1, const float* __restrict__ b1,
    const float* __restrict__ W2, const float* __restrict__ b2,
    const float* __restrict__ W3, const float* __restrict__ b3,
    float* __restrict__ Ei, float* __restrict__ dE)
{
    __shared__ float xsh[4][F];
    __shared__ float h1sh[4][H];
    __shared__ float aux[4][H];

    const int tid  = threadIdx.x;
    const int lane = tid & 63;
    const int wave = tid >> 6;
    const int atom = blockIdx.x * 4 + wave;   // < B*N

    if (lane < F) xsh[wave][lane] = image[atom * F + lane];
    __syncthreads();

    // layer 1: a1[i] = b1[i] + sum_f x[f] * W1[f,i]   (W1 reads coalesced over i)
    float a1 = b1[lane];
    #pragma unroll
    for (int f = 0; f < F; ++f) a1 = fmaf(xsh[wave][f], W1[f * H + lane], a1);
    const float h1 = tanhf(a1);
    h1sh[wave][lane] = h1;
    __syncthreads();

    // layer 2
    float a2 = b2[lane];
    #pragma unroll 8
    for (int j = 0; j < H; ++j) a2 = fmaf(h1sh[wave][j], W2[j * H + lane], a2);
    const float h2 = tanhf(a2);
    const float w3 = W3[lane];

    // E = sum_i h2[i]*W3[i] + b3 : butterfly-free down-shuffle reduce over 64 lanes
    float t = h2 * w3;
    #pragma unroll
    for (int off = 32; off > 0; off >>= 1) t += __shfl_down(t, off);
    if (lane == 0) Ei[atom] = t + b3[0];

    // g2
    aux[wave][lane] = w3 * (1.0f - h2 * h2);
    __syncthreads();

    // g1[i] = (1-h1[i]^2) * sum_j W2[i,j] * g2[j]
    float s = 0.0f;
    #pragma unroll 8
    for (int j = 0; j < H; ++j) s = fmaf(W2[lane * H + j], aux[wave][j], s);
    const float g1 = s * (1.0f - h1 * h1);
    h1sh[wave][lane] = g1;          // h1sh no longer read (last read was pre-sync)
    __syncthreads();

    // dE[f] = sum_i W1[f,i] * g1[i]
    if (lane < F) {
        float dx = 0.0f;
        #pragma unroll 8
        for (int i = 0; i < H; ++i) dx = fmaf(W1[lane * H + i], h1sh[wave][i], dx);
        dE[atom * F + lane] = dx;
    }
}

// ---------------------------------------------------------------------------
// Kernel 2: Etot[b] = sum_n Ei[b,n]  (deterministic fixed-order reduction)
// ---------------------------------------------------------------------------
__global__ __launch_bounds__(256) void etot_kernel(
    const float* __restrict__ Ei, float* __restrict__ Etot)
{
    __shared__ float red[4];
    const int b = blockIdx.x, tid = threadIdx.x;
    float s = 0.0f;
    for (int i = tid; i < N; i += 256) s += Ei[b * N + i];
    #pragma unroll
    for (int off = 32; off > 0; off >>= 1) s += __shfl_down(s, off);
    const int lane = tid & 63, wave = tid >> 6;
    if (lane == 0) red[wave] = s;
    __syncthreads();
    if (tid == 0) Etot[b] = (red[0] + red[1]) + (red[2] + red[3]);
}

// ---------------------------------------------------------------------------
// Kernel 3: Force[b,n,d] = sum_{k,f} dE[b, nb(b,n,k)-1, f] * dfeat[b,n,k,f,d]
// One block per atom (b,n). dfeat slice per atom: 100*42*3 floats contiguous.
// Each thread handles (k,f) pairs -> 12 contiguous bytes of dfeat per pair
// (wave reads 768B contiguous). dE gather stays L2-resident (688 KB total).
// neighbor == 0 means "no neighbor" (padded zero row).
// ---------------------------------------------------------------------------
__global__ __launch_bounds__(256) void force_kernel(
    const float* __restrict__ dE, const float* __restrict__ dfeat,
    const int* __restrict__ neighbor, float* __restrict__ force)
{
    __shared__ int   nsh[K];
    __shared__ float red[4][3];

    const int tid = threadIdx.x;
    const int bn  = blockIdx.x;            // b*N + n
    const int b   = bn >> 10;              // N = 1024

    if (tid < K) nsh[tid] = neighbor[bn * K + tid];
    __syncthreads();

    const float* df  = dfeat + (size_t)bn * (K * F * 3);
    const float* dEb = dE + (size_t)b * (N * F);

    float fx = 0.0f, fy = 0.0f, fz = 0.0f;
    for (int p = tid; p < K * F; p += 256) {
        const int k  = p / F;
        const int f  = p - k * F;
        const int nb = nsh[k];
        const float de = (nb > 0) ? dEb[(nb - 1) * F + f] : 0.0f;
        const int base = p * 3;
        fx = fmaf(de, df[base + 0], fx);
        fy = fmaf(de, df[base + 1], fy);
        fz = fmaf(de, df[base + 2], fz);
    }

    #pragma unroll
    for (int off = 32; off > 0; off >>= 1) {
        fx += __shfl_down(fx, off);
        fy += __shfl_down(fy, off);
        fz += __shfl_down(fz, off);
    }
    const int lane = tid & 63, wave = tid >> 6;
    if (lane == 0) { red[wave][0] = fx; red[wave][1] = fy; red[wave][2] = fz; }
    __syncthreads();
    if (tid == 0) {
        force[bn * 3 + 0] = (red[0][0] + red[1][0]) + (red[2][0] + red[3][0]);
        force[bn * 3 + 1] = (red[0][1] + red[1][1]) + (red[2][1] + red[3][1]);
        force[bn * 3 + 2] = (red[0][2] + red[1][2]) + (red[2][2] + red[3][2]);
    }
}

extern "C" void kernel_launch(void* const* d_in, const int* in_sizes, int n_in,
                              void* d_out, int out_size, void* d_ws, size_t ws_size,
                              hipStream_t stream)
{
    const float* image    = (const float*)d_in[0];
    const float* dfeat    = (const float*)d_in[1];
    const int*   neighbor = (const int*)d_in[2];
    // d_in[3] Egroup_weight, d_in[4] divider: unused by the reference outputs
    const float* W1 = (const float*)d_in[5];
    const float* b1 = (const float*)d_in[6];
    const float* W2 = (const float*)d_in[7];
    const float* b2 = (const float*)d_in[8];
    const float* W3 = (const float*)d_in[9];
    const float* b3 = (const float*)d_in[10];

    float* out   = (float*)d_out;
    float* Etot  = out;                 // [B]
    float* Ei    = out + B;             // [B,N]
    float* Force = out + B + B * N;     // [B,N,3]
    float* dE    = (float*)d_ws;        // [B,N,F] = 688,128 bytes

    mlp_kernel<<<(B * N) / 4, 256, 0, stream>>>(image, W1, b1, W2, b2, W3, b3, Ei, dE);
    etot_kernel<<<B, 256, 0, stream>>>(Ei, Etot);
    force_kernel<<<B * N, 256, 0, stream>>>(dE, dfeat, neighbor, Force);
}